// Round 4
// baseline (210.969 us; speedup 1.0000x reference)
//
#include <hip/hip_runtime.h>
#include <stdint.h>

// ---- AdEx constants ----
#define THRC      (-50.4f)
#define ELC       (-70.6f)
#define V_RESETC  (-70.6f)
#define DT_GL_C   (0.10676156583629893f)   // DT*GL/C
#define DELTATC   (2.0f)
#define DT_C      (0.0035587188612099642f) // DT/C
#define DT_TAUW   (0.006944444444444444f)  // DT/TAUW
#define DTA_TAUW  (0.027777777777777776f)  // DT*A/TAUW
#define BCONST    (0.0805f)
#define EXPCLIP   (281.0f)                 // 30 / DT_GL__C

#define M_TOT 8192
#define UNITS 1024
#define K_TOT 1792   // [Xhi 256 | Xlo 256 | Xhi 256 | Z 1024]
#define CH    (8192*1024)
#define NKSTEPS (K_TOT/32)   // 56

typedef __attribute__((ext_vector_type(8))) short s16x8;
typedef __attribute__((ext_vector_type(4))) float f32x4;

__device__ __forceinline__ unsigned short f2bf(float f) {
  union { float f; unsigned int u; } v; v.f = f;
  unsigned int r = v.u + 0x7fffu + ((v.u >> 16) & 1u);  // RNE
  return (unsigned short)(r >> 16);
}
__device__ __forceinline__ float bf2f(unsigned short h) {
  union { unsigned int u; float f; } v; v.u = ((unsigned int)h) << 16; return v.f;
}

// ---- build A = [Xhi | Xlo | Xhi | Zbf16], row-major 8192 x 1792 bf16 (LINEAR) ----
__global__ __launch_bounds__(256) void build_a(const float* __restrict__ X,
                                               const float* __restrict__ Z,
                                               unsigned short* __restrict__ A) {
  int o = blockIdx.x * 256 + threadIdx.x;       // octet index, 8192*224 total
  int row = o / 224;
  int c8 = (o - row * 224) * 8;
  const float* src; bool lo = false;
  if (c8 < 256)        { src = X + (size_t)row * 256 + c8; }
  else if (c8 < 512)   { src = X + (size_t)row * 256 + (c8 - 256); lo = true; }
  else if (c8 < 768)   { src = X + (size_t)row * 256 + (c8 - 512); }
  else                 { src = Z + (size_t)row * 1024 + (c8 - 768); }
  float4 f0 = *(const float4*)(src);
  float4 f1 = *(const float4*)(src + 4);
  float fv[8] = {f0.x, f0.y, f0.z, f0.w, f1.x, f1.y, f1.z, f1.w};
  unsigned short h[8];
#pragma unroll
  for (int i = 0; i < 8; ++i) {
    unsigned short hi = f2bf(fv[i]);
    h[i] = lo ? f2bf(fv[i] - bf2f(hi)) : hi;
  }
  uint4 pk;
  pk.x = (unsigned)h[0] | ((unsigned)h[1] << 16);
  pk.y = (unsigned)h[2] | ((unsigned)h[3] << 16);
  pk.z = (unsigned)h[4] | ((unsigned)h[5] << 16);
  pk.w = (unsigned)h[6] | ((unsigned)h[7] << 16);
  *(uint4*)(A + (size_t)row * K_TOT + c8) = pk;
}

// ---- build B^T (N-major 1024 x 1792 bf16): [Wi_hi; Wi_hi; Wi_lo; Wr_nodiag] (LINEAR) ----
__global__ __launch_bounds__(256) void build_b(const float* __restrict__ Wi,
                                               const float* __restrict__ Wr,
                                               unsigned short* __restrict__ BT) {
  __shared__ unsigned short tile[32][33];
  int tx = threadIdx.x & 31, ty = threadIdx.x >> 5;
  int k0 = blockIdx.x * 32, n0 = blockIdx.y * 32;
#pragma unroll
  for (int j = 0; j < 4; ++j) {
    int kk = k0 + ty + j * 8;
    int n  = n0 + tx;
    float f; bool lo = false;
    if (kk < 256)       f = Wi[(size_t)kk * 1024 + n];
    else if (kk < 512)  f = Wi[(size_t)(kk - 256) * 1024 + n];
    else if (kk < 768) { f = Wi[(size_t)(kk - 512) * 1024 + n]; lo = true; }
    else { int kr = kk - 768; f = (kr == n) ? 0.0f : Wr[(size_t)kr * 1024 + n]; }
    unsigned short h = f2bf(f);
    if (lo) h = f2bf(f - bf2f(h));
    tile[ty + j * 8][tx] = h;
  }
  __syncthreads();
#pragma unroll
  for (int j = 0; j < 4; ++j) {
    int n  = n0 + ty + j * 8;
    int kk = k0 + tx;
    BT[(size_t)n * K_TOT + kk] = tile[tx][ty + j * 8];
  }
}

// ---- fused GEMM (i_t) + AdEx epilogue, NO LDS / NO BARRIERS ----
// One wave per block, 64x64 output tile, acc 4x4 of 16x16x32 MFMA.
// A/B fragments loaded straight global->VGPR (16B/lane, 64B-segment coalesced).
// Full K-unroll: one basic block, all offsets fold into 13-bit imm, scheduler
// hoists loads across steps and overlaps epilogue state loads with MFMA tail.
__global__ __launch_bounds__(64) void adex_gemm(
    const unsigned short* __restrict__ A, const unsigned short* __restrict__ BT,
    const float* __restrict__ oV, const int* __restrict__ oR,
    const float* __restrict__ oW, const float* __restrict__ oZ,
    float* __restrict__ out)
{
  const int lane = threadIdx.x;
  const int l15 = lane & 15, l4 = lane >> 4;

  // Bijective XCD swizzle (2048 % 8 == 0): XCD x gets swz [x*256, x*256+256).
  // n-fastest: one XCD covers 16 m-strips (3.7 MB of A) x all 16 n-tiles.
  const int bid = blockIdx.x;
  const int swz = (bid & 7) * 256 + (bid >> 3);
  const int nt = swz & 15;          // 16 n-tiles
  const int mt = swz >> 4;          // 128 m-tiles
  const int rowA0 = mt * 64;
  const int colB0 = nt * 64;

  // Fragment base pointers: lane reads A[row = base + f*16 + l15][k = l4*8 .. +8]
  const unsigned short* pA0 = A  + (size_t)(rowA0 +  0 + l15) * K_TOT + l4 * 8;
  const unsigned short* pA1 = A  + (size_t)(rowA0 + 16 + l15) * K_TOT + l4 * 8;
  const unsigned short* pA2 = A  + (size_t)(rowA0 + 32 + l15) * K_TOT + l4 * 8;
  const unsigned short* pA3 = A  + (size_t)(rowA0 + 48 + l15) * K_TOT + l4 * 8;
  const unsigned short* pB0 = BT + (size_t)(colB0 +  0 + l15) * K_TOT + l4 * 8;
  const unsigned short* pB1 = BT + (size_t)(colB0 + 16 + l15) * K_TOT + l4 * 8;
  const unsigned short* pB2 = BT + (size_t)(colB0 + 32 + l15) * K_TOT + l4 * 8;
  const unsigned short* pB3 = BT + (size_t)(colB0 + 48 + l15) * K_TOT + l4 * 8;

  f32x4 acc[4][4];
#pragma unroll
  for (int i = 0; i < 4; ++i)
#pragma unroll
    for (int j = 0; j < 4; ++j) acc[i][j] = (f32x4){0.f, 0.f, 0.f, 0.f};

#pragma unroll
  for (int s = 0; s < NKSTEPS; ++s) {
    const int o = s * 32;           // 64 B per step, folds into imm offset (<4096)
    s16x8 af[4], bf[4];
    af[0] = *(const s16x8*)(pA0 + o);
    af[1] = *(const s16x8*)(pA1 + o);
    af[2] = *(const s16x8*)(pA2 + o);
    af[3] = *(const s16x8*)(pA3 + o);
    bf[0] = *(const s16x8*)(pB0 + o);
    bf[1] = *(const s16x8*)(pB1 + o);
    bf[2] = *(const s16x8*)(pB2 + o);
    bf[3] = *(const s16x8*)(pB3 + o);
#pragma unroll
    for (int i = 0; i < 4; ++i)
#pragma unroll
      for (int j = 0; j < 4; ++j)
        acc[i][j] = __builtin_amdgcn_mfma_f32_16x16x32_bf16(af[i], bf[j], acc[i][j], 0, 0, 0);
  }

  // Epilogue: C/D layout col = lane&15, row = (lane>>4)*4 + reg
#pragma unroll
  for (int i = 0; i < 4; ++i) {
    int mBase = rowA0 + i * 16 + l4 * 4;
#pragma unroll
    for (int j = 0; j < 4; ++j) {
      int u = colB0 + j * 16 + l15;
#pragma unroll
      for (int r = 0; r < 4; ++r) {
        int m = mBase + r;
        size_t idx = (size_t)m * UNITS + u;
        float it = acc[i][j][r];
        float ov = oV[idx];
        float ow = oW[idx];
        float oz = oZ[idx];
        int   orr = oR[idx];
        float ex = expf((ov - THRC) * 0.5f);          // /DELTAT
        ex = fminf(ex, EXPCLIP);
        float nv = ov - DT_GL_C * (ov - ELC) + (DT_GL_C * DELTATC) * ex + (it - ow) * DT_C;
        nv = (oz > 0.5f) ? V_RESETC : nv;
        float nw = ow - DT_TAUW * ow + DTA_TAUW * (ov - ELC) + BCONST * oz;
        float nz = (nv > THRC) ? 1.0f : 0.0f;
        if (orr > 0) nz = 0.0f;
        int nr = orr - 1 + (nz > 0.5f ? 5 : 0);
        nr = nr < 0 ? 0 : (nr > 5 ? 5 : nr);
        out[idx]           = nv;
        out[CH + idx]      = nz;
        out[2 * CH + idx]  = (float)nr;
        out[3 * CH + idx]  = nw;
      }
    }
  }
}

extern "C" void kernel_launch(void* const* d_in, const int* in_sizes, int n_in,
                              void* d_out, int out_size, void* d_ws, size_t ws_size,
                              hipStream_t stream) {
  const float* X  = (const float*)d_in[0];
  const float* oV = (const float*)d_in[1];
  const int*   oR = (const int*)d_in[2];
  const float* oW = (const float*)d_in[3];
  const float* oZ = (const float*)d_in[4];
  const float* Wi = (const float*)d_in[5];
  const float* Wr = (const float*)d_in[6];
  unsigned short* Aall = (unsigned short*)d_ws;                       // 29.36 MB
  unsigned short* BT   = Aall + (size_t)M_TOT * K_TOT;                //  3.67 MB
  float* out = (float*)d_out;

  hipLaunchKernelGGL(build_a, dim3((M_TOT * (K_TOT / 8)) / 256), dim3(256), 0, stream, X, oZ, Aall);
  hipLaunchKernelGGL(build_b, dim3(K_TOT / 32, UNITS / 32), dim3(256), 0, stream, Wi, Wr, BT);
  hipLaunchKernelGGL(adex_gemm, dim3((M_TOT / 64) * (UNITS / 64)), dim3(64), 0, stream,
                     Aall, BT, oV, oR, oW, oZ, out);
}

// Round 5
// 186.643 us; speedup vs baseline: 1.1303x; 1.1303x over previous
//
#include <hip/hip_runtime.h>
#include <stdint.h>

// ---- AdEx constants ----
#define THRC      (-50.4f)
#define ELC       (-70.6f)
#define V_RESETC  (-70.6f)
#define DT_GL_C   (0.10676156583629893f)   // DT*GL/C
#define DELTATC   (2.0f)
#define DT_C      (0.0035587188612099642f) // DT/C
#define DT_TAUW   (0.006944444444444444f)  // DT/TAUW
#define DTA_TAUW  (0.027777777777777776f)  // DT*A/TAUW
#define BCONST    (0.0805f)
#define EXPCLIP   (281.0f)                 // 30 / DT_GL__C

#define M_TOT 8192
#define UNITS 1024
#define K_TOT 1792   // [Xhi 256 | Xlo 256 | Xhi 256 | Z 1024]
#define CH    (8192*1024)
#define NKSTEPS (K_TOT/32)   // 56

typedef __attribute__((ext_vector_type(8))) short s16x8;
typedef __attribute__((ext_vector_type(4))) float f32x4;

__device__ __forceinline__ unsigned short f2bf(float f) {
  union { float f; unsigned int u; } v; v.f = f;
  unsigned int r = v.u + 0x7fffu + ((v.u >> 16) & 1u);  // RNE
  return (unsigned short)(r >> 16);
}
__device__ __forceinline__ float bf2f(unsigned short h) {
  union { unsigned int u; float f; } v; v.u = ((unsigned int)h) << 16; return v.f;
}

// ---- build A = [Xhi | Xlo | Xhi | Zbf16], row-major 8192 x 1792 bf16 (LINEAR) ----
__global__ __launch_bounds__(256) void build_a(const float* __restrict__ X,
                                               const float* __restrict__ Z,
                                               unsigned short* __restrict__ A) {
  int o = blockIdx.x * 256 + threadIdx.x;       // octet index, 8192*224 total
  int row = o / 224;
  int c8 = (o - row * 224) * 8;
  const float* src; bool lo = false;
  if (c8 < 256)        { src = X + (size_t)row * 256 + c8; }
  else if (c8 < 512)   { src = X + (size_t)row * 256 + (c8 - 256); lo = true; }
  else if (c8 < 768)   { src = X + (size_t)row * 256 + (c8 - 512); }
  else                 { src = Z + (size_t)row * 1024 + (c8 - 768); }
  float4 f0 = *(const float4*)(src);
  float4 f1 = *(const float4*)(src + 4);
  float fv[8] = {f0.x, f0.y, f0.z, f0.w, f1.x, f1.y, f1.z, f1.w};
  unsigned short h[8];
#pragma unroll
  for (int i = 0; i < 8; ++i) {
    unsigned short hi = f2bf(fv[i]);
    h[i] = lo ? f2bf(fv[i] - bf2f(hi)) : hi;
  }
  uint4 pk;
  pk.x = (unsigned)h[0] | ((unsigned)h[1] << 16);
  pk.y = (unsigned)h[2] | ((unsigned)h[3] << 16);
  pk.z = (unsigned)h[4] | ((unsigned)h[5] << 16);
  pk.w = (unsigned)h[6] | ((unsigned)h[7] << 16);
  *(uint4*)(A + (size_t)row * K_TOT + c8) = pk;
}

// ---- build B^T (N-major 1024 x 1792 bf16): [Wi_hi; Wi_hi; Wi_lo; Wr_nodiag] (LINEAR) ----
__global__ __launch_bounds__(256) void build_b(const float* __restrict__ Wi,
                                               const float* __restrict__ Wr,
                                               unsigned short* __restrict__ BT) {
  __shared__ unsigned short tile[32][33];
  int tx = threadIdx.x & 31, ty = threadIdx.x >> 5;
  int k0 = blockIdx.x * 32, n0 = blockIdx.y * 32;
#pragma unroll
  for (int j = 0; j < 4; ++j) {
    int kk = k0 + ty + j * 8;
    int n  = n0 + tx;
    float f; bool lo = false;
    if (kk < 256)       f = Wi[(size_t)kk * 1024 + n];
    else if (kk < 512)  f = Wi[(size_t)(kk - 256) * 1024 + n];
    else if (kk < 768) { f = Wi[(size_t)(kk - 512) * 1024 + n]; lo = true; }
    else { int kr = kk - 768; f = (kr == n) ? 0.0f : Wr[(size_t)kr * 1024 + n]; }
    unsigned short h = f2bf(f);
    if (lo) h = f2bf(f - bf2f(h));
    tile[ty + j * 8][tx] = h;
  }
  __syncthreads();
#pragma unroll
  for (int j = 0; j < 4; ++j) {
    int n  = n0 + ty + j * 8;
    int kk = k0 + tx;
    BT[(size_t)n * K_TOT + kk] = tile[tx][ty + j * 8];
  }
}

// ---- fused GEMM (i_t) + AdEx epilogue, NO LDS / NO BARRIERS ----
// One wave per block, 64x64 tile, acc 4x4. Global->VGPR fragment loads with an
// EXPLICIT 2-buffer register pipeline (static indices only — rule #20), so step
// s+1's 8 loads are in flight while step s's 16 MFMAs run. __launch_bounds__(64,2)
// caps VGPR at 256 so the allocator can hold both buffers (R4's 88-VGPR allocation
// serialized every load: 200us).
__global__ __launch_bounds__(64, 2) void adex_gemm(
    const unsigned short* __restrict__ A, const unsigned short* __restrict__ BT,
    const float* __restrict__ oV, const int* __restrict__ oR,
    const float* __restrict__ oW, const float* __restrict__ oZ,
    float* __restrict__ out)
{
  const int lane = threadIdx.x;
  const int l15 = lane & 15, l4 = lane >> 4;

  // Bijective XCD swizzle (2048 % 8 == 0), n-fastest within an XCD:
  // 16 consecutive blocks on one XCD share the same A-strip (L2 reuse), B fits L2.
  const int bid = blockIdx.x;
  const int swz = (bid & 7) * 256 + (bid >> 3);
  const int nt = swz & 15;          // 16 n-tiles
  const int mt = swz >> 4;          // 128 m-tiles
  const int rowA0 = mt * 64;
  const int colB0 = nt * 64;

  const unsigned short* pA0 = A  + (size_t)(rowA0 +  0 + l15) * K_TOT + l4 * 8;
  const unsigned short* pA1 = A  + (size_t)(rowA0 + 16 + l15) * K_TOT + l4 * 8;
  const unsigned short* pA2 = A  + (size_t)(rowA0 + 32 + l15) * K_TOT + l4 * 8;
  const unsigned short* pA3 = A  + (size_t)(rowA0 + 48 + l15) * K_TOT + l4 * 8;
  const unsigned short* pB0 = BT + (size_t)(colB0 +  0 + l15) * K_TOT + l4 * 8;
  const unsigned short* pB1 = BT + (size_t)(colB0 + 16 + l15) * K_TOT + l4 * 8;
  const unsigned short* pB2 = BT + (size_t)(colB0 + 32 + l15) * K_TOT + l4 * 8;
  const unsigned short* pB3 = BT + (size_t)(colB0 + 48 + l15) * K_TOT + l4 * 8;

  f32x4 acc[4][4];
#pragma unroll
  for (int i = 0; i < 4; ++i)
#pragma unroll
    for (int j = 0; j < 4; ++j) acc[i][j] = (f32x4){0.f, 0.f, 0.f, 0.f};

  s16x8 fa[2][4], fb[2][4];

#define LOADSTEP(buf, s)                                   \
  do {                                                     \
    const int o_ = (s) * 32;                               \
    fa[buf][0] = *(const s16x8*)(pA0 + o_);                \
    fa[buf][1] = *(const s16x8*)(pA1 + o_);                \
    fa[buf][2] = *(const s16x8*)(pA2 + o_);                \
    fa[buf][3] = *(const s16x8*)(pA3 + o_);                \
    fb[buf][0] = *(const s16x8*)(pB0 + o_);                \
    fb[buf][1] = *(const s16x8*)(pB1 + o_);                \
    fb[buf][2] = *(const s16x8*)(pB2 + o_);                \
    fb[buf][3] = *(const s16x8*)(pB3 + o_);                \
  } while (0)

  LOADSTEP(0, 0);
#pragma unroll
  for (int s = 0; s < NKSTEPS; ++s) {       // full unroll -> all buf indices static
    const int c = s & 1;
    if (s + 1 < NKSTEPS) LOADSTEP(c ^ 1, s + 1);   // prefetch next step
#pragma unroll
    for (int i = 0; i < 4; ++i)
#pragma unroll
      for (int j = 0; j < 4; ++j)
        acc[i][j] = __builtin_amdgcn_mfma_f32_16x16x32_bf16(fa[c][i], fb[c][j], acc[i][j], 0, 0, 0);
  }
#undef LOADSTEP

  // Epilogue: C/D layout col = lane&15, row = (lane>>4)*4 + reg
#pragma unroll
  for (int i = 0; i < 4; ++i) {
    int mBase = rowA0 + i * 16 + l4 * 4;
#pragma unroll
    for (int j = 0; j < 4; ++j) {
      int u = colB0 + j * 16 + l15;
#pragma unroll
      for (int r = 0; r < 4; ++r) {
        int m = mBase + r;
        size_t idx = (size_t)m * UNITS + u;
        float it = acc[i][j][r];
        float ov = oV[idx];
        float ow = oW[idx];
        float oz = oZ[idx];
        int   orr = oR[idx];
        float ex = expf((ov - THRC) * 0.5f);          // /DELTAT
        ex = fminf(ex, EXPCLIP);
        float nv = ov - DT_GL_C * (ov - ELC) + (DT_GL_C * DELTATC) * ex + (it - ow) * DT_C;
        nv = (oz > 0.5f) ? V_RESETC : nv;
        float nw = ow - DT_TAUW * ow + DTA_TAUW * (ov - ELC) + BCONST * oz;
        float nz = (nv > THRC) ? 1.0f : 0.0f;
        if (orr > 0) nz = 0.0f;
        int nr = orr - 1 + (nz > 0.5f ? 5 : 0);
        nr = nr < 0 ? 0 : (nr > 5 ? 5 : nr);
        out[idx]           = nv;
        out[CH + idx]      = nz;
        out[2 * CH + idx]  = (float)nr;
        out[3 * CH + idx]  = nw;
      }
    }
  }
}

extern "C" void kernel_launch(void* const* d_in, const int* in_sizes, int n_in,
                              void* d_out, int out_size, void* d_ws, size_t ws_size,
                              hipStream_t stream) {
  const float* X  = (const float*)d_in[0];
  const float* oV = (const float*)d_in[1];
  const int*   oR = (const int*)d_in[2];
  const float* oW = (const float*)d_in[3];
  const float* oZ = (const float*)d_in[4];
  const float* Wi = (const float*)d_in[5];
  const float* Wr = (const float*)d_in[6];
  unsigned short* Aall = (unsigned short*)d_ws;                       // 29.36 MB
  unsigned short* BT   = Aall + (size_t)M_TOT * K_TOT;                //  3.67 MB
  float* out = (float*)d_out;

  hipLaunchKernelGGL(build_a, dim3((M_TOT * (K_TOT / 8)) / 256), dim3(256), 0, stream, X, oZ, Aall);
  hipLaunchKernelGGL(build_b, dim3(K_TOT / 32, UNITS / 32), dim3(256), 0, stream, Wi, Wr, BT);
  hipLaunchKernelGGL(adex_gemm, dim3((M_TOT / 64) * (UNITS / 64)), dim3(64), 0, stream,
                     Aall, BT, oV, oR, oW, oZ, out);
}

// Round 6
// 182.665 us; speedup vs baseline: 1.1550x; 1.0218x over previous
//
#include <hip/hip_runtime.h>
#include <stdint.h>
#include <type_traits>

// ---- AdEx constants ----
#define THRC      (-50.4f)
#define ELC       (-70.6f)
#define V_RESETC  (-70.6f)
#define DT_GL_C   (0.10676156583629893f)   // DT*GL/C
#define DELTATC   (2.0f)
#define DT_C      (0.0035587188612099642f) // DT/C
#define DT_TAUW   (0.006944444444444444f)  // DT/TAUW
#define DTA_TAUW  (0.027777777777777776f)  // DT*A/TAUW
#define BCONST    (0.0805f)
#define EXPCLIP   (281.0f)                 // 30 / DT_GL__C

#define M_TOT 8192
#define UNITS 1024
#define K_TOT 1792   // [Xhi 256 | Xlo 256 | Xhi 256 | Z 1024]
#define CH    (8192*1024)
#define NKSTEPS (K_TOT/32)   // 56

typedef __attribute__((ext_vector_type(8))) short s16x8;
typedef __attribute__((ext_vector_type(4))) float f32x4;

__device__ __forceinline__ unsigned short f2bf(float f) {
  union { float f; unsigned int u; } v; v.f = f;
  unsigned int r = v.u + 0x7fffu + ((v.u >> 16) & 1u);  // RNE
  return (unsigned short)(r >> 16);
}
__device__ __forceinline__ float bf2f(unsigned short h) {
  union { unsigned int u; float f; } v; v.u = ((unsigned int)h) << 16; return v.f;
}

// ---- build A = [Xhi | Xlo | Xhi | Zbf16], row-major 8192 x 1792 bf16 (LINEAR) ----
__global__ __launch_bounds__(256) void build_a(const float* __restrict__ X,
                                               const float* __restrict__ Z,
                                               unsigned short* __restrict__ A) {
  int o = blockIdx.x * 256 + threadIdx.x;       // octet index, 8192*224 total
  int row = o / 224;
  int c8 = (o - row * 224) * 8;
  const float* src; bool lo = false;
  if (c8 < 256)        { src = X + (size_t)row * 256 + c8; }
  else if (c8 < 512)   { src = X + (size_t)row * 256 + (c8 - 256); lo = true; }
  else if (c8 < 768)   { src = X + (size_t)row * 256 + (c8 - 512); }
  else                 { src = Z + (size_t)row * 1024 + (c8 - 768); }
  float4 f0 = *(const float4*)(src);
  float4 f1 = *(const float4*)(src + 4);
  float fv[8] = {f0.x, f0.y, f0.z, f0.w, f1.x, f1.y, f1.z, f1.w};
  unsigned short h[8];
#pragma unroll
  for (int i = 0; i < 8; ++i) {
    unsigned short hi = f2bf(fv[i]);
    h[i] = lo ? f2bf(fv[i] - bf2f(hi)) : hi;
  }
  uint4 pk;
  pk.x = (unsigned)h[0] | ((unsigned)h[1] << 16);
  pk.y = (unsigned)h[2] | ((unsigned)h[3] << 16);
  pk.z = (unsigned)h[4] | ((unsigned)h[5] << 16);
  pk.w = (unsigned)h[6] | ((unsigned)h[7] << 16);
  *(uint4*)(A + (size_t)row * K_TOT + c8) = pk;
}

// ---- build B^T (N-major 1024 x 1792 bf16): [Wi_hi; Wi_hi; Wi_lo; Wr_nodiag] (LINEAR) ----
__global__ __launch_bounds__(256) void build_b(const float* __restrict__ Wi,
                                               const float* __restrict__ Wr,
                                               unsigned short* __restrict__ BT) {
  __shared__ unsigned short tile[32][33];
  int tx = threadIdx.x & 31, ty = threadIdx.x >> 5;
  int k0 = blockIdx.x * 32, n0 = blockIdx.y * 32;
#pragma unroll
  for (int j = 0; j < 4; ++j) {
    int kk = k0 + ty + j * 8;
    int n  = n0 + tx;
    float f; bool lo = false;
    if (kk < 256)       f = Wi[(size_t)kk * 1024 + n];
    else if (kk < 512)  f = Wi[(size_t)(kk - 256) * 1024 + n];
    else if (kk < 768) { f = Wi[(size_t)(kk - 512) * 1024 + n]; lo = true; }
    else { int kr = kk - 768; f = (kr == n) ? 0.0f : Wr[(size_t)kr * 1024 + n]; }
    unsigned short h = f2bf(f);
    if (lo) h = f2bf(f - bf2f(h));
    tile[ty + j * 8][tx] = h;
  }
  __syncthreads();
#pragma unroll
  for (int j = 0; j < 4; ++j) {
    int n  = n0 + ty + j * 8;
    int kk = k0 + tx;
    BT[(size_t)n * K_TOT + kk] = tile[tx][ty + j * 8];
  }
}

// compile-time unrolled for: f(integral_constant<int,I>) for I in [I0, N)
template <int I, int N, typename F>
__device__ __forceinline__ void unroll_for(F&& f) {
  if constexpr (I < N) {
    f(std::integral_constant<int, I>{});
    unroll_for<I + 1, N>(f);
  }
}

// ---- fused GEMM (i_t) + AdEx epilogue, NO LDS / NO BARRIERS ----
// One wave per block, 64x64 tile, acc 4x4 of 16x16x32 MFMA.
// Fragments loaded by INLINE-ASM global_load_dwordx4 into a 4-deep register
// pipeline with counted vmcnt(24) (3 steps always in flight). The asm defs
// force the allocator to keep all 4 buffers live — R4/R5 showed the compiler
// otherwise allocates 84 VGPRs and serializes every load (200us).
__global__ __launch_bounds__(64, 2) void adex_gemm(
    const unsigned short* __restrict__ A, const unsigned short* __restrict__ BT,
    const float* __restrict__ oV, const int* __restrict__ oR,
    const float* __restrict__ oW, const float* __restrict__ oZ,
    float* __restrict__ out)
{
  const int lane = threadIdx.x;
  const int l15 = lane & 15, l4 = lane >> 4;

  // Bijective XCD swizzle (2048 % 8 == 0), n-fastest within an XCD:
  // 16 consecutive swz ids on one XCD share the same 3.7MB A-strip; B (3.7MB) L2-resident.
  const int bid = blockIdx.x;
  const int swz = (bid & 7) * 256 + (bid >> 3);
  const int nt = swz & 15;          // 16 n-tiles
  const int mt = swz >> 4;          // 128 m-tiles
  const int rowA0 = mt * 64;
  const int colB0 = nt * 64;

  const unsigned short* pA0 = A  + (size_t)(rowA0 +  0 + l15) * K_TOT + l4 * 8;
  const unsigned short* pA1 = A  + (size_t)(rowA0 + 16 + l15) * K_TOT + l4 * 8;
  const unsigned short* pA2 = A  + (size_t)(rowA0 + 32 + l15) * K_TOT + l4 * 8;
  const unsigned short* pA3 = A  + (size_t)(rowA0 + 48 + l15) * K_TOT + l4 * 8;
  const unsigned short* pB0 = BT + (size_t)(colB0 +  0 + l15) * K_TOT + l4 * 8;
  const unsigned short* pB1 = BT + (size_t)(colB0 + 16 + l15) * K_TOT + l4 * 8;
  const unsigned short* pB2 = BT + (size_t)(colB0 + 32 + l15) * K_TOT + l4 * 8;
  const unsigned short* pB3 = BT + (size_t)(colB0 + 48 + l15) * K_TOT + l4 * 8;

  f32x4 acc[4][4];
#pragma unroll
  for (int i = 0; i < 4; ++i)
#pragma unroll
    for (int j = 0; j < 4; ++j) acc[i][j] = (f32x4){0.f, 0.f, 0.f, 0.f};

  s16x8 fa[4][4], fb[4][4];   // 4-deep pipeline; all indices compile-time constants

#define LD(dst, ptr, off)                                        \
  asm volatile("global_load_dwordx4 %0, %1, off offset:%2"       \
               : "=v"(dst) : "v"(ptr), "n"(off) : "memory")

#define ISSUE_STEP(buf, off64)              \
  do {                                      \
    LD(fa[buf][0], pA0, off64);             \
    LD(fa[buf][1], pA1, off64);             \
    LD(fa[buf][2], pA2, off64);             \
    LD(fa[buf][3], pA3, off64);             \
    LD(fb[buf][0], pB0, off64);             \
    LD(fb[buf][1], pB1, off64);             \
    LD(fb[buf][2], pB2, off64);             \
    LD(fb[buf][3], pB3, off64);             \
  } while (0)

  // prologue: 3 steps in flight (24 loads)
  ISSUE_STEP(0, 0);
  ISSUE_STEP(1, 64);
  ISSUE_STEP(2, 128);

  unroll_for<0, NKSTEPS>([&](auto Sc) {
    constexpr int s = decltype(Sc)::value;
    constexpr int b = s & 3;
    if constexpr (s + 3 < NKSTEPS) {
      constexpr int nb = (s + 3) & 3;
      ISSUE_STEP(nb, (s + 3) * 64);                       // 64 B per K-step, imm <= 3520
      asm volatile("s_waitcnt vmcnt(24)" ::: "memory");   // step s's 8 loads done; 24 stay in flight
    } else {
      constexpr int w = (NKSTEPS - 1 - s) * 8;            // 16, 8, 0 on the tail
      asm volatile("s_waitcnt vmcnt(%0)" :: "n"(w) : "memory");
    }
    __builtin_amdgcn_sched_barrier(0);                    // rule 18: pin MFMAs below the wait
#pragma unroll
    for (int i = 0; i < 4; ++i)
#pragma unroll
      for (int j = 0; j < 4; ++j)
        acc[i][j] = __builtin_amdgcn_mfma_f32_16x16x32_bf16(fa[b][i], fb[b][j], acc[i][j], 0, 0, 0);
  });
#undef ISSUE_STEP
#undef LD

  // Epilogue: C/D layout col = lane&15, row = (lane>>4)*4 + reg
#pragma unroll
  for (int i = 0; i < 4; ++i) {
    int mBase = rowA0 + i * 16 + l4 * 4;
#pragma unroll
    for (int j = 0; j < 4; ++j) {
      int u = colB0 + j * 16 + l15;
#pragma unroll
      for (int r = 0; r < 4; ++r) {
        int m = mBase + r;
        size_t idx = (size_t)m * UNITS + u;
        float it = acc[i][j][r];
        float ov = oV[idx];
        float ow = oW[idx];
        float oz = oZ[idx];
        int   orr = oR[idx];
        float ex = expf((ov - THRC) * 0.5f);          // /DELTAT
        ex = fminf(ex, EXPCLIP);
        float nv = ov - DT_GL_C * (ov - ELC) + (DT_GL_C * DELTATC) * ex + (it - ow) * DT_C;
        nv = (oz > 0.5f) ? V_RESETC : nv;
        float nw = ow - DT_TAUW * ow + DTA_TAUW * (ov - ELC) + BCONST * oz;
        float nz = (nv > THRC) ? 1.0f : 0.0f;
        if (orr > 0) nz = 0.0f;
        int nr = orr - 1 + (nz > 0.5f ? 5 : 0);
        nr = nr < 0 ? 0 : (nr > 5 ? 5 : nr);
        out[idx]           = nv;
        out[CH + idx]      = nz;
        out[2 * CH + idx]  = (float)nr;
        out[3 * CH + idx]  = nw;
      }
    }
  }
}

extern "C" void kernel_launch(void* const* d_in, const int* in_sizes, int n_in,
                              void* d_out, int out_size, void* d_ws, size_t ws_size,
                              hipStream_t stream) {
  const float* X  = (const float*)d_in[0];
  const float* oV = (const float*)d_in[1];
  const int*   oR = (const int*)d_in[2];
  const float* oW = (const float*)d_in[3];
  const float* oZ = (const float*)d_in[4];
  const float* Wi = (const float*)d_in[5];
  const float* Wr = (const float*)d_in[6];
  unsigned short* Aall = (unsigned short*)d_ws;                       // 29.36 MB
  unsigned short* BT   = Aall + (size_t)M_TOT * K_TOT;                //  3.67 MB
  float* out = (float*)d_out;

  hipLaunchKernelGGL(build_a, dim3((M_TOT * (K_TOT / 8)) / 256), dim3(256), 0, stream, X, oZ, Aall);
  hipLaunchKernelGGL(build_b, dim3(K_TOT / 32, UNITS / 32), dim3(256), 0, stream, Wi, Wr, BT);
  hipLaunchKernelGGL(adex_gemm, dim3((M_TOT / 64) * (UNITS / 64)), dim3(64), 0, stream,
                     Aall, BT, oV, oR, oW, oZ, out);
}